// Round 14
// baseline (673.995 us; speedup 1.0000x reference)
//
#include <hip/hip_runtime.h>
#include <math.h>

#define L_    9216
#define WIN   144
#define NWIN  64
#define KJ    432

typedef __bf16 bf16x8 __attribute__((ext_vector_type(8)));
typedef unsigned short u16x8 __attribute__((ext_vector_type(8)));
typedef float f32x4 __attribute__((ext_vector_type(4)));

__device__ __forceinline__ unsigned short f2bf(float f) {
    unsigned int u = __builtin_bit_cast(unsigned int, f);
    u = (u + 0x7FFFu + ((u >> 16) & 1u)) >> 16;
    return (unsigned short)u;
}
__device__ __forceinline__ float bf2f(unsigned short u) {
    return __builtin_bit_cast(float, (unsigned int)u << 16);
}
__device__ __forceinline__ void load_lds16(const float* g, float* l) {
    __builtin_amdgcn_global_load_lds(
        (const __attribute__((address_space(1))) void*)g,
        (__attribute__((address_space(3))) void*)l, 16, 0, 0);
}

// ---------------- weight pre-transpose for conv3x3 (+ zero region) ----------------
__global__ void k_wprep(const float* __restrict__ wm, float* __restrict__ wtr,
                        float* __restrict__ zeros) {
    int s = blockIdx.x * 256 + threadIdx.x;       // 147456 total
    if (s < 147456) {
        int cq = s & 63, r = s >> 6;              // r = c*9+kk
        wtr[s] = wm[(size_t)cq * 2304 + r];
    }
    if (blockIdx.x == 0 && threadIdx.x < 64) zeros[threadIdx.x] = 0.f;
}

// ---------------- conv3x3 v10: split-K x2, 2 h-rows/block, async staging ----------
__global__ __launch_bounds__(256) void k_conv3x3(const float* __restrict__ x,
                                                 const float* __restrict__ wtr,
                                                 const float* __restrict__ zeros,
                                                 float* __restrict__ parts) {
    __shared__ __align__(16) float stg[2][3840];   // 960 f4 slots per buffer
    const int bid = blockIdx.x;
    const int half = bid & 1;
    const int hp = (bid >> 1) % 48, n = bid / 96;
    const int chb = half * 128;
    const int t = threadIdx.x;
    const int hsel = t >> 7;                        // wave-pair selects output row
    const int t128 = t & 127;
    const int cg = t128 & 15, wg = t128 >> 4;
    const int w0 = wg * 12, cq0 = cg * 4;
    const int h = hp * 2 + hsel;
    const float* xb = x + (size_t)n * 256 * 9216;

    int grel[4], gkind[4];                 // 0=x, 1=w, 2=zeros, 3=skip
#pragma unroll
    for (int c = 0; c < 4; ++c) {
        int s = c * 256 + t;
        if (s < 384) {
            int ch = s / 96, rr = (s % 96) / 24, q = s % 24;
            int hh = hp * 2 - 1 + rr;
            if (hh >= 0 && hh < 96) { gkind[c] = 0; grel[c] = ch * 9216 + hh * 96 + q * 4; }
            else                    { gkind[c] = 2; grel[c] = 0; }
        } else if (s < 960) {
            int u = s - 384;
            int ch = u / 144, kk = (u % 144) >> 4, q = u & 15;
            gkind[c] = 1; grel[c] = ch * 576 + kk * 64 + q * 4;
        } else {
            gkind[c] = 3; grel[c] = 0;
        }
    }
    const int wvbase = t & 192;

#define C3_STAGE(buf, cb)                                                         \
    do {                                                                          \
        _Pragma("unroll")                                                         \
        for (int c = 0; c < 4; ++c) {                                             \
            if (gkind[c] != 3) {                                                  \
                const float* g = (gkind[c] == 0) ? (xb + (size_t)(cb) * 9216 + grel[c]) \
                               : (gkind[c] == 1) ? (wtr + (size_t)(cb) * 576 + grel[c]) \
                                                 : zeros;                         \
                load_lds16(g, &stg[buf][(c * 256 + wvbase) * 4]);                 \
            }                                                                     \
        }                                                                         \
    } while (0)

    float acc[12][4];
#pragma unroll
    for (int j = 0; j < 12; ++j)
#pragma unroll
        for (int q = 0; q < 4; ++q) acc[j][q] = 0.f;

    C3_STAGE(0, chb);
    __syncthreads();

    const int liIdx = (wg == 0) ? 0 : (w0 - 1);
    const int riIdx = (wg == 7) ? 95 : (w0 + 12);

    for (int it = 0; it < 32; ++it) {
        const int cur = it & 1;
        if (it < 31) C3_STAGE(cur ^ 1, chb + (it + 1) * 4);
        const float* xs = stg[cur];
        const float* ws = stg[cur] + 1536;
#pragma unroll
        for (int ch = 0; ch < 4; ++ch) {
#pragma unroll
            for (int dh = 0; dh < 3; ++dh) {
                const float* xrow = xs + ch * 384 + (hsel + dh) * 96;
                float4 wv0 = *(const float4*)(ws + ch * 576 + (dh * 3 + 0) * 64 + cq0);
                float4 wv1 = *(const float4*)(ws + ch * 576 + (dh * 3 + 1) * 64 + cq0);
                float4 wv2 = *(const float4*)(ws + ch * 576 + (dh * 3 + 2) * 64 + cq0);
                float xf[14];
                {
                    float lv = xrow[liIdx];
                    xf[0] = (wg == 0) ? 0.f : lv;
                    float4 a = *(const float4*)(xrow + w0);
                    float4 b = *(const float4*)(xrow + w0 + 4);
                    float4 c4v = *(const float4*)(xrow + w0 + 8);
                    xf[1] = a.x;  xf[2] = a.y;  xf[3] = a.z;  xf[4] = a.w;
                    xf[5] = b.x;  xf[6] = b.y;  xf[7] = b.z;  xf[8] = b.w;
                    xf[9] = c4v.x; xf[10] = c4v.y; xf[11] = c4v.z; xf[12] = c4v.w;
                    float rv = xrow[riIdx];
                    xf[13] = (wg == 7) ? 0.f : rv;
                }
#pragma unroll
                for (int j = 0; j < 12; ++j) {
                    acc[j][0] += xf[j] * wv0.x;
                    acc[j][1] += xf[j] * wv0.y;
                    acc[j][2] += xf[j] * wv0.z;
                    acc[j][3] += xf[j] * wv0.w;
                }
#pragma unroll
                for (int j = 0; j < 12; ++j) {
                    acc[j][0] += xf[j + 1] * wv1.x;
                    acc[j][1] += xf[j + 1] * wv1.y;
                    acc[j][2] += xf[j + 1] * wv1.z;
                    acc[j][3] += xf[j + 1] * wv1.w;
                }
#pragma unroll
                for (int j = 0; j < 12; ++j) {
                    acc[j][0] += xf[j + 2] * wv2.x;
                    acc[j][1] += xf[j + 2] * wv2.y;
                    acc[j][2] += xf[j + 2] * wv2.z;
                    acc[j][3] += xf[j + 2] * wv2.w;
                }
            }
        }
        __syncthreads();
    }
#undef C3_STAGE

    float* pb = parts + (size_t)half * 4718592;
#pragma unroll
    for (int j = 0; j < 12; ++j) {
        float4 o = {acc[j][0], acc[j][1], acc[j][2], acc[j][3]};
        *(float4*)&pb[((size_t)n * L_ + (size_t)h * 96 + w0 + j) * 64 + cq0] = o;
    }
}

// ---------------- combine split-K partials + bias -> xe ----------------
__global__ __launch_bounds__(256) void k_c3sum(const float* __restrict__ parts,
                                               const float* __restrict__ bm,
                                               float* __restrict__ xe) {
    size_t i = (size_t)blockIdx.x * 256 + threadIdx.x;   // f4 index; grid 4608
    float4 a = ((const float4*)parts)[i];
    float4 b = ((const float4*)parts)[i + 1179648];
    float4 bi = ((const float4*)bm)[i & 15];
    float4 o = {a.x + b.x + bi.x, a.y + b.y + bi.y, a.z + b.z + bi.z, a.w + b.w + bi.w};
    ((float4*)xe)[i] = o;
}

// ---------------- conv1x1 via bf16 MFMA -> yeb bf16 [8,9216,256] ----------------
__global__ __launch_bounds__(256) void k_conv1x1(const float* __restrict__ x,
                                                 const float* __restrict__ wa,
                                                 const float* __restrict__ ba,
                                                 unsigned short* __restrict__ yeb) {
    __shared__ __align__(16) unsigned short pA[64 * 40];  // [co][k], pad 40
    __shared__ __align__(16) unsigned short pB[32 * 68];  // [k][l],  pad 68
    __shared__ __align__(16) float det[64 * 67];          // [co][l], pad 67
    const int bid = blockIdx.x;
    const int n = bid / 576, rem = bid % 576;
    const int l0 = (rem >> 2) * 64, co0 = (rem & 3) * 64;
    const int t = threadIdx.x, lane = t & 63, nq = t >> 6;

    f32x4 acc[4];
#pragma unroll
    for (int nt = 0; nt < 4; ++nt) { f32x4 z = {0.f, 0.f, 0.f, 0.f}; acc[nt] = z; }

    const int aOff = (nq * 16 + (lane & 15)) * 40 + (lane >> 4) * 8;
    const int bK = (lane >> 4) * 8, bL = lane & 15;

    for (int kc = 0; kc < 8; ++kc) {
        const int c0 = kc * 32;
        __syncthreads();
        for (int s = t; s < 512; s += 256) {
            int co = s >> 3, q = s & 7;
            float4 v = *(const float4*)&wa[(size_t)(co0 + co) * 256 + c0 + q * 4];
            ushort4 b = {f2bf(v.x), f2bf(v.y), f2bf(v.z), f2bf(v.w)};
            *(ushort4*)&pA[co * 40 + q * 4] = b;
        }
        for (int s = t; s < 512; s += 256) {
            int c = s >> 4, l4 = s & 15;
            float4 v = *(const float4*)&x[((size_t)n * 256 + c0 + c) * L_ + l0 + l4 * 4];
            ushort4 b = {f2bf(v.x), f2bf(v.y), f2bf(v.z), f2bf(v.w)};
            *(ushort4*)&pB[c * 68 + l4 * 4] = b;
        }
        __syncthreads();
        u16x8 au = *(const u16x8*)&pA[aOff];
        bf16x8 af = __builtin_bit_cast(bf16x8, au);
#pragma unroll
        for (int nt = 0; nt < 4; ++nt) {
            u16x8 bu;
#pragma unroll
            for (int j = 0; j < 8; ++j) bu[j] = pB[(bK + j) * 68 + nt * 16 + bL];
            bf16x8 bf = __builtin_bit_cast(bf16x8, bu);
            acc[nt] = __builtin_amdgcn_mfma_f32_16x16x32_bf16(af, bf, acc[nt], 0, 0, 0);
        }
    }
    __syncthreads();
#pragma unroll
    for (int nt = 0; nt < 4; ++nt)
#pragma unroll
        for (int r = 0; r < 4; ++r)
            det[(nq * 16 + (lane >> 4) * 4 + r) * 67 + nt * 16 + (lane & 15)] = acc[nt][r];
    __syncthreads();
    for (int s = t; s < 512; s += 256) {
        int l = s >> 3, c8 = s & 7;       // 8 co per slot
        u16x8 o;
#pragma unroll
        for (int e = 0; e < 8; ++e) {
            int co = c8 * 8 + e;
            o[e] = f2bf(det[co * 67 + l] + ba[co0 + co]);
        }
        *(u16x8*)&yeb[((size_t)n * L_ + l0 + l) * 256 + co0 + c8 * 8] = o;
    }
}

// ---------------- kmeans assign (fp64 dot; norm is argmax-invariant) ----------------
__global__ __launch_bounds__(256) void k_assign(const float* __restrict__ xe,
                                                const float* __restrict__ means,
                                                int* __restrict__ codes_i,
                                                float* __restrict__ codes_f) {
    __shared__ float sm[128 * 64];
    for (int s = threadIdx.x; s < 8192; s += 256) sm[s] = means[s];
    __syncthreads();
    const int g = blockIdx.x * 256 + threadIdx.x;
    const float* row = xe + (size_t)g * 64;
    float v[64];
#pragma unroll
    for (int c4 = 0; c4 < 16; c4++) {
        float4 t4 = *(const float4*)(row + c4 * 4);
        v[c4 * 4 + 0] = t4.x; v[c4 * 4 + 1] = t4.y; v[c4 * 4 + 2] = t4.z; v[c4 * 4 + 3] = t4.w;
    }
    int best = 0;
    double bd = -1e300;
    for (int cl = 0; cl < 128; cl++) {
        double d = 0.0;
#pragma unroll
        for (int c4 = 0; c4 < 16; c4++) {
            float4 m4 = *(const float4*)(sm + cl * 64 + c4 * 4);
            d += (double)v[c4 * 4 + 0] * (double)m4.x + (double)v[c4 * 4 + 1] * (double)m4.y +
                 (double)v[c4 * 4 + 2] * (double)m4.z + (double)v[c4 * 4 + 3] * (double)m4.w;
        }
        if (d > bd) { bd = d; best = cl; }
    }
    codes_i[g] = best;
    codes_f[g] = (float)best;
}

// ---------------- stable counting sort ----------------
__global__ void k_hist(const int* __restrict__ codes_i, int* __restrict__ hist) {
    __shared__ int h[128];
    if (threadIdx.x < 128) h[threadIdx.x] = 0;
    __syncthreads();
    int n = blockIdx.x / 36, ch = blockIdx.x % 36;
    int c = codes_i[n * L_ + ch * 256 + threadIdx.x];
    atomicAdd(&h[c], 1);
    __syncthreads();
    if (threadIdx.x < 128) hist[(n * 36 + ch) * 128 + threadIdx.x] = h[threadIdx.x];
}

__global__ void k_scan(const int* __restrict__ hist, int* __restrict__ basebuf) {
    __shared__ int tot[128];
    __shared__ int binstart[128];
    int n = blockIdx.x, c = threadIdx.x;
    int run = 0;
    int local[36];
    for (int ch = 0; ch < 36; ch++) { local[ch] = run; run += hist[(n * 36 + ch) * 128 + c]; }
    tot[c] = run;
    __syncthreads();
    if (c == 0) {
        int s = 0;
        for (int b = 0; b < 128; b++) { binstart[b] = s; s += tot[b]; }
    }
    __syncthreads();
    int bs0 = binstart[c];
    for (int ch = 0; ch < 36; ch++) basebuf[(n * 36 + ch) * 128 + c] = bs0 + local[ch];
}

__global__ void k_rank(const int* __restrict__ codes_i, const int* __restrict__ basebuf,
                       int* __restrict__ idxb) {
    __shared__ int sc[256];
    __shared__ int sb[128];
    int n = blockIdx.x / 36, ch = blockIdx.x % 36;
    int i = threadIdx.x;
    int l = ch * 256 + i;
    int c = codes_i[n * L_ + l];
    sc[i] = c;
    if (i < 128) sb[i] = basebuf[(n * 36 + ch) * 128 + i];
    __syncthreads();
    int r = 0;
    for (int j = 0; j < i; j++) r += (sc[j] == c);
    int pos = sb[c] + r;
    idxb[n * L_ + pos] = l;
}

// ---------------- QK v2: 2-pass bf16 MFMA, writes PROBS directly + bs ----------
// Pass 1: MFMA all tiles, online (m,s) in regs only. Combine lanes (shfl) and
// waves (LDS) -> block-wide smax/sinv in LDS. Pass 2: recompute MFMA, write
// p = exp(v-m)*sinv to score. Identical arithmetic to prior raw+apply path.
__global__ __launch_bounds__(256) void k_qk_mfma(const float* __restrict__ xe,
                                                 const int* __restrict__ idxb,
                                                 float* __restrict__ score,
                                                 float* __restrict__ bs) {
    __shared__ __align__(16) unsigned short kb[432 * 72];
    __shared__ float snorm[144];
    __shared__ int sidx[432];
    __shared__ float pm[4][144], ps[4][144];
    __shared__ float fsm[144], fsv[144];
    const int bid = blockIdx.x;
    const int n = bid >> 6, k = bid & 63;
    const int t = threadIdx.x, lane = t & 63, nq = t >> 6;

    for (int s = t; s < 432; s += 256) {
        int wb = s / 144, jj = s % 144;
        int wk = (wb == 0) ? k : (wb == 1) ? ((k + 63) & 63) : ((k + 1) & 63);
        sidx[s] = idxb[n * L_ + wk * WIN + jj];
    }
    __syncthreads();
    for (int s = t; s < 6912; s += 256) {
        int row = s >> 4, q4 = s & 15;
        float4 v = *(const float4*)(xe + ((size_t)n * L_ + sidx[row]) * 64 + q4 * 4);
        float ss = v.x * v.x + v.y * v.y + v.z * v.z + v.w * v.w;
        ss += __shfl_xor(ss, 1); ss += __shfl_xor(ss, 2);
        ss += __shfl_xor(ss, 4); ss += __shfl_xor(ss, 8);
        float nr = fmaxf(sqrtf(ss), 5e-5f);
        float inv = 1.0f / nr;
        ushort4 b = {f2bf(v.x * inv), f2bf(v.y * inv), f2bf(v.z * inv), f2bf(v.w * inv)};
        *(ushort4*)&kb[row * 72 + q4 * 4] = b;
        if (q4 == 0 && row < 144) snorm[row] = nr;
    }
    __syncthreads();
    const int arow = lane & 15, aks = (lane >> 4) * 8;
    bf16x8 af[9][2];
#pragma unroll
    for (int mt = 0; mt < 9; ++mt) {
        af[mt][0] = *(const bf16x8*)&kb[(mt * 16 + arow) * 72 + aks];
        af[mt][1] = *(const bf16x8*)&kb[(mt * 16 + arow) * 72 + 32 + aks];
    }
    float sc[9][4];
#pragma unroll
    for (int mt = 0; mt < 9; ++mt)
#pragma unroll
        for (int r = 0; r < 4; ++r)
            sc[mt][r] = snorm[mt * 16 + (lane >> 4) * 4 + r];

    // ---- pass 1: stats only ----
    float rm[9][4], rs[9][4];
#pragma unroll
    for (int mt = 0; mt < 9; ++mt)
#pragma unroll
        for (int r = 0; r < 4; ++r) { rm[mt][r] = -1e30f; rs[mt][r] = 0.f; }

    for (int nt = nq; nt < 27; nt += 4) {
        const int col = nt * 16 + (lane & 15);
        bf16x8 b0 = *(const bf16x8*)&kb[col * 72 + aks];
        bf16x8 b1 = *(const bf16x8*)&kb[col * 72 + 32 + aks];
#pragma unroll
        for (int mt = 0; mt < 9; ++mt) {
            f32x4 acc = {0.f, 0.f, 0.f, 0.f};
            acc = __builtin_amdgcn_mfma_f32_16x16x32_bf16(af[mt][0], b0, acc, 0, 0, 0);
            acc = __builtin_amdgcn_mfma_f32_16x16x32_bf16(af[mt][1], b1, acc, 0, 0, 0);
#pragma unroll
            for (int r = 0; r < 4; ++r) {
                float v = acc[r] * sc[mt][r];
                float mo = rm[mt][r];
                float mn = fmaxf(mo, v);
                rs[mt][r] = rs[mt][r] * __expf(mo - mn) + __expf(v - mn);
                rm[mt][r] = mn;
            }
        }
    }
#pragma unroll
    for (int mt = 0; mt < 9; ++mt)
#pragma unroll
        for (int r = 0; r < 4; ++r) {
            float m = rm[mt][r], s = rs[mt][r];
#pragma unroll
            for (int off = 1; off < 16; off <<= 1) {
                float om = __shfl_xor(m, off);
                float os = __shfl_xor(s, off);
                float M = fmaxf(m, om);
                s = s * __expf(m - M) + os * __expf(om - M);
                m = M;
            }
            rm[mt][r] = m; rs[mt][r] = s;
        }
    if ((lane & 15) == 0) {
#pragma unroll
        for (int mt = 0; mt < 9; ++mt)
#pragma unroll
            for (int r = 0; r < 4; ++r) {
                int row = mt * 16 + (lane >> 4) * 4 + r;
                pm[nq][row] = rm[mt][r];
                ps[nq][row] = rs[mt][r];
            }
    }
    __syncthreads();
    if (t < 144) {
        float M = pm[0][t], S = ps[0][t];
#pragma unroll
        for (int w = 1; w < 4; ++w) {
            float m2 = pm[w][t], s2 = ps[w][t];
            float Mn = fmaxf(M, m2);
            S = S * __expf(M - Mn) + s2 * __expf(m2 - Mn);
            M = Mn;
        }
        bs[(size_t)(n * NWIN + k) * WIN + t] = M + logf(S);
        fsm[t] = M;
        fsv[t] = 1.f / S;
    }
    __syncthreads();

    // ---- pass 2: recompute + write probs ----
    float qm[9][4], qiv[9][4];
#pragma unroll
    for (int mt = 0; mt < 9; ++mt)
#pragma unroll
        for (int r = 0; r < 4; ++r) {
            int row = mt * 16 + (lane >> 4) * 4 + r;
            qm[mt][r] = fsm[row];
            qiv[mt][r] = fsv[row];
        }
    float* rbase = score + (size_t)(n * NWIN + k) * WIN * KJ;
    for (int nt = nq; nt < 27; nt += 4) {
        const int col = nt * 16 + (lane & 15);
        bf16x8 b0 = *(const bf16x8*)&kb[col * 72 + aks];
        bf16x8 b1 = *(const bf16x8*)&kb[col * 72 + 32 + aks];
#pragma unroll
        for (int mt = 0; mt < 9; ++mt) {
            f32x4 acc = {0.f, 0.f, 0.f, 0.f};
            acc = __builtin_amdgcn_mfma_f32_16x16x32_bf16(af[mt][0], b0, acc, 0, 0, 0);
            acc = __builtin_amdgcn_mfma_f32_16x16x32_bf16(af[mt][1], b1, acc, 0, 0, 0);
#pragma unroll
            for (int r = 0; r < 4; ++r) {
                float v = acc[r] * sc[mt][r];
                float p = __expf(v - qm[mt][r]) * qiv[mt][r];
                rbase[(size_t)(mt * 16 + (lane >> 4) * 4 + r) * KJ + col] = p;
            }
        }
    }
}

// ---------------- PV v2: reads probs, MFMA, retb (token order, bf16) ----------
__global__ __launch_bounds__(256) void k_pv_sm(const unsigned short* __restrict__ yeb,
                                               const int* __restrict__ idxb,
                                               const float* __restrict__ score,
                                               unsigned short* __restrict__ retb) {
    __shared__ __align__(16) unsigned short pA[144 * 72];   // P[i][kk], stride 72
    __shared__ __align__(16) unsigned short pB[64 * 264];   // Y[kk][co], stride 264
    __shared__ int sidx[432];
    const int bid = blockIdx.x;
    const int n = bid >> 6, k = bid & 63;
    const int t = threadIdx.x, lane = t & 63, nq = t >> 6;

    for (int s = t; s < 432; s += 256) {
        int wb = s / 144, jj = s % 144;
        int wk = (wb == 0) ? k : (wb == 1) ? ((k + 63) & 63) : ((k + 1) & 63);
        sidx[s] = idxb[n * L_ + wk * WIN + jj];
    }

    f32x4 acc[9][4];
#pragma unroll
    for (int mt = 0; mt < 9; ++mt)
#pragma unroll
        for (int nt = 0; nt < 4; ++nt) {
            f32x4 z = {0.f, 0.f, 0.f, 0.f};
            acc[mt][nt] = z;
        }

    const float* srow = score + (size_t)(n * NWIN + k) * WIN * KJ;
    const int aBase = (lane & 15) * 72 + (lane >> 4) * 8;
    const int bBase = (lane >> 4) * 8 * 264 + nq * 64 + (lane & 15);

    for (int kc = 0; kc < 7; ++kc) {
        __syncthreads();
        for (int s = t; s < 2304; s += 256) {
            int i = s >> 4, c4 = s & 15;
            int kcol = kc * 64 + c4 * 4;
            ushort4 b = {0, 0, 0, 0};
            if (kcol < KJ) {
                float4 p = *(const float4*)(srow + (size_t)i * KJ + kcol);
                b.x = f2bf(p.x); b.y = f2bf(p.y); b.z = f2bf(p.z); b.w = f2bf(p.w);
            }
            *(ushort4*)&pA[i * 72 + c4 * 4] = b;
        }
        for (int s = t; s < 2048; s += 256) {
            int j = s >> 5, c8 = s & 31;
            int kk = kc * 64 + j;
            u16x8 u = {0, 0, 0, 0, 0, 0, 0, 0};
            if (kk < KJ) u = *(const u16x8*)&yeb[(size_t)sidx[kk] * 256 +
                                                (size_t)n * L_ * 256 + c8 * 8];
            *(u16x8*)&pB[j * 264 + c8 * 8] = u;
        }
        __syncthreads();
#pragma unroll
        for (int ks = 0; ks < 2; ++ks) {
            bf16x8 af[9];
#pragma unroll
            for (int mt = 0; mt < 9; ++mt)
                af[mt] = *(const bf16x8*)&pA[aBase + mt * 1152 + ks * 32];
#pragma unroll
            for (int nt = 0; nt < 4; ++nt) {
                const int e = bBase + ks * 32 * 264 + nt * 16;
                u16x8 bu;
#pragma unroll
                for (int j = 0; j < 8; ++j) bu[j] = pB[e + j * 264];
                bf16x8 bf = __builtin_bit_cast(bf16x8, bu);
#pragma unroll
                for (int mt = 0; mt < 9; ++mt)
                    acc[mt][nt] = __builtin_amdgcn_mfma_f32_16x16x32_bf16(af[mt], bf, acc[mt][nt], 0, 0, 0);
            }
        }
    }
    const int rowb = (lane >> 4) * 4;
    const int colb = nq * 64 + (lane & 15);
#pragma unroll
    for (int mt = 0; mt < 9; ++mt)
#pragma unroll
        for (int nt = 0; nt < 4; ++nt)
#pragma unroll
            for (int r = 0; r < 4; ++r) {
                int row = mt * 16 + rowb + r;
                int tok = sidx[row];
                retb[((size_t)n * L_ + tok) * 256 + colb + nt * 16] = f2bf(acc[mt][nt][r]);
            }
}

// ---------------- final: out = x + 0.1 * retb (token order, bf16) ----------------
__global__ __launch_bounds__(256) void k_out(const float* __restrict__ x,
                                             const unsigned short* __restrict__ retb,
                                             float* __restrict__ out) {
    __shared__ float sr[32 * 257];
    const int n = blockIdx.x / 288, lt = blockIdx.x % 288;
    const int lbase = lt * 32;
    const int t = threadIdx.x;
    for (int s = t; s < 1024; s += 256) {
        int lr = s >> 5, c8 = s & 31;
        u16x8 u = *(const u16x8*)&retb[((size_t)n * L_ + lbase + lr) * 256 + c8 * 8];
#pragma unroll
        for (int e = 0; e < 8; ++e) sr[lr * 257 + c8 * 8 + e] = bf2f(u[e]);
    }
    __syncthreads();
    const int lr = t & 31, cog = t >> 5;
    for (int cc = 0; cc < 32; cc++) {
        int co = cog * 32 + cc;
        size_t gi = ((size_t)(n * 256 + co)) * L_ + lbase + lr;
        out[gi] = x[gi] + 0.1f * sr[lr * 257 + co];
    }
}

extern "C" void kernel_launch(void* const* d_in, const int* in_sizes, int n_in,
                              void* d_out, int out_size, void* d_ws, size_t ws_size,
                              hipStream_t stream) {
    (void)in_sizes; (void)n_in; (void)out_size; (void)ws_size;
    const float* x     = (const float*)d_in[0];
    const float* means = (const float*)d_in[1];
    const float* wm    = (const float*)d_in[2];
    const float* bm    = (const float*)d_in[3];
    const float* wa    = (const float*)d_in[4];
    const float* ba    = (const float*)d_in[5];

    float* out   = (float*)d_out;
    float* score = out + (size_t)8 * 256 * L_;
    float* bs    = score + (size_t)8 * NWIN * WIN * KJ;
    float* codesf = bs + (size_t)8 * L_;

    float* xe  = (float*)d_ws;
    float* ye  = xe + (size_t)8 * L_ * 64;                  // region reused as bf16 yeb
    float* ret = ye + (size_t)8 * L_ * 256;                 // parts (f32) then retb (bf16)
    float* wtr = ret + (size_t)8 * L_ * 256;
    int* codes_i = (int*)(wtr + 147456);
    int* idxb    = codes_i + 8 * L_;
    int* undo    = idxb + 8 * L_;                           // unused, keeps layout
    int* hist    = undo + 8 * L_;
    int* basebuf = hist + 8 * 36 * 128;
    float* zeros = (float*)(basebuf + 8 * 36 * 128);

    float* parts = ret;
    unsigned short* yeb  = (unsigned short*)ye;
    unsigned short* retb = (unsigned short*)ret;

    k_wprep  <<<576, 256, 0, stream>>>(wm, wtr, zeros);
    k_conv3x3<<<768, 256, 0, stream>>>(x, wtr, zeros, parts);
    k_c3sum  <<<4608, 256, 0, stream>>>(parts, bm, xe);
    k_conv1x1<<<4608, 256, 0, stream>>>(x, wa, ba, yeb);
    k_assign <<<288, 256, 0, stream>>>(xe, means, codes_i, codesf);
    k_hist   <<<288, 256, 0, stream>>>(codes_i, hist);
    k_scan   <<<8, 128, 0, stream>>>(hist, basebuf);
    k_rank   <<<288, 256, 0, stream>>>(codes_i, basebuf, idxb);
    k_qk_mfma<<<512, 256, 0, stream>>>(xe, idxb, score, bs);
    k_pv_sm  <<<512, 256, 0, stream>>>(yeb, idxb, score, retb);
    k_out    <<<2304, 256, 0, stream>>>(x, retb, out);
}

// Round 15
// 656.458 us; speedup vs baseline: 1.0267x; 1.0267x over previous
//
#include <hip/hip_runtime.h>
#include <math.h>

#define L_    9216
#define WIN   144
#define NWIN  64
#define KJ    432

typedef __bf16 bf16x8 __attribute__((ext_vector_type(8)));
typedef unsigned short u16x8 __attribute__((ext_vector_type(8)));
typedef float f32x4 __attribute__((ext_vector_type(4)));

__device__ __forceinline__ unsigned short f2bf(float f) {
    unsigned int u = __builtin_bit_cast(unsigned int, f);
    u = (u + 0x7FFFu + ((u >> 16) & 1u)) >> 16;
    return (unsigned short)u;
}
__device__ __forceinline__ float bf2f(unsigned short u) {
    return __builtin_bit_cast(float, (unsigned int)u << 16);
}
__device__ __forceinline__ void load_lds16(const float* g, float* l) {
    __builtin_amdgcn_global_load_lds(
        (const __attribute__((address_space(1))) void*)g,
        (__attribute__((address_space(3))) void*)l, 16, 0, 0);
}

// ---------------- weight pre-transpose for conv3x3 (+ zero region) ----------------
__global__ void k_wprep(const float* __restrict__ wm, float* __restrict__ wtr,
                        float* __restrict__ zeros) {
    int s = blockIdx.x * 256 + threadIdx.x;       // 147456 total
    if (s < 147456) {
        int cq = s & 63, r = s >> 6;              // r = c*9+kk
        wtr[s] = wm[(size_t)cq * 2304 + r];
    }
    if (blockIdx.x == 0 && threadIdx.x < 64) zeros[threadIdx.x] = 0.f;
}

// ---------------- conv3x3 v11: split-K x4, 2 h-rows/block, async staging ----------
// grid 1536 ((n*48+hp)*4+q), block 256 (4 waves); 64 ch per block, 16 iters of 4.
__global__ __launch_bounds__(256) void k_conv3x3(const float* __restrict__ x,
                                                 const float* __restrict__ wtr,
                                                 const float* __restrict__ zeros,
                                                 float* __restrict__ parts) {
    __shared__ __align__(16) float stg[2][3840];   // 960 f4 slots per buffer
    const int bid = blockIdx.x;
    const int quarter = bid & 3;
    const int hp = (bid >> 2) % 48, n = bid / 192;
    const int chb = quarter * 64;
    const int t = threadIdx.x;
    const int hsel = t >> 7;                        // wave-pair selects output row
    const int t128 = t & 127;
    const int cg = t128 & 15, wg = t128 >> 4;
    const int w0 = wg * 12, cq0 = cg * 4;
    const int h = hp * 2 + hsel;
    const float* xb = x + (size_t)n * 256 * 9216;

    int grel[4], gkind[4];                 // 0=x, 1=w, 2=zeros, 3=skip
#pragma unroll
    for (int c = 0; c < 4; ++c) {
        int s = c * 256 + t;
        if (s < 384) {
            int ch = s / 96, rr = (s % 96) / 24, q = s % 24;
            int hh = hp * 2 - 1 + rr;
            if (hh >= 0 && hh < 96) { gkind[c] = 0; grel[c] = ch * 9216 + hh * 96 + q * 4; }
            else                    { gkind[c] = 2; grel[c] = 0; }
        } else if (s < 960) {
            int u = s - 384;
            int ch = u / 144, kk = (u % 144) >> 4, q = u & 15;
            gkind[c] = 1; grel[c] = ch * 576 + kk * 64 + q * 4;
        } else {
            gkind[c] = 3; grel[c] = 0;
        }
    }
    const int wvbase = t & 192;

#define C3_STAGE(buf, cb)                                                         \
    do {                                                                          \
        _Pragma("unroll")                                                         \
        for (int c = 0; c < 4; ++c) {                                             \
            if (gkind[c] != 3) {                                                  \
                const float* g = (gkind[c] == 0) ? (xb + (size_t)(cb) * 9216 + grel[c]) \
                               : (gkind[c] == 1) ? (wtr + (size_t)(cb) * 576 + grel[c]) \
                                                 : zeros;                         \
                load_lds16(g, &stg[buf][(c * 256 + wvbase) * 4]);                 \
            }                                                                     \
        }                                                                         \
    } while (0)

    float acc[12][4];
#pragma unroll
    for (int j = 0; j < 12; ++j)
#pragma unroll
        for (int q = 0; q < 4; ++q) acc[j][q] = 0.f;

    C3_STAGE(0, chb);
    __syncthreads();

    const int liIdx = (wg == 0) ? 0 : (w0 - 1);
    const int riIdx = (wg == 7) ? 95 : (w0 + 12);

    for (int it = 0; it < 16; ++it) {
        const int cur = it & 1;
        if (it < 15) C3_STAGE(cur ^ 1, chb + (it + 1) * 4);
        const float* xs = stg[cur];
        const float* ws = stg[cur] + 1536;
#pragma unroll
        for (int ch = 0; ch < 4; ++ch) {
#pragma unroll
            for (int dh = 0; dh < 3; ++dh) {
                const float* xrow = xs + ch * 384 + (hsel + dh) * 96;
                float4 wv0 = *(const float4*)(ws + ch * 576 + (dh * 3 + 0) * 64 + cq0);
                float4 wv1 = *(const float4*)(ws + ch * 576 + (dh * 3 + 1) * 64 + cq0);
                float4 wv2 = *(const float4*)(ws + ch * 576 + (dh * 3 + 2) * 64 + cq0);
                float xf[14];
                {
                    float lv = xrow[liIdx];
                    xf[0] = (wg == 0) ? 0.f : lv;
                    float4 a = *(const float4*)(xrow + w0);
                    float4 b = *(const float4*)(xrow + w0 + 4);
                    float4 c4v = *(const float4*)(xrow + w0 + 8);
                    xf[1] = a.x;  xf[2] = a.y;  xf[3] = a.z;  xf[4] = a.w;
                    xf[5] = b.x;  xf[6] = b.y;  xf[7] = b.z;  xf[8] = b.w;
                    xf[9] = c4v.x; xf[10] = c4v.y; xf[11] = c4v.z; xf[12] = c4v.w;
                    float rv = xrow[riIdx];
                    xf[13] = (wg == 7) ? 0.f : rv;
                }
#pragma unroll
                for (int j = 0; j < 12; ++j) {
                    acc[j][0] += xf[j] * wv0.x;
                    acc[j][1] += xf[j] * wv0.y;
                    acc[j][2] += xf[j] * wv0.z;
                    acc[j][3] += xf[j] * wv0.w;
                }
#pragma unroll
                for (int j = 0; j < 12; ++j) {
                    acc[j][0] += xf[j + 1] * wv1.x;
                    acc[j][1] += xf[j + 1] * wv1.y;
                    acc[j][2] += xf[j + 1] * wv1.z;
                    acc[j][3] += xf[j + 1] * wv1.w;
                }
#pragma unroll
                for (int j = 0; j < 12; ++j) {
                    acc[j][0] += xf[j + 2] * wv2.x;
                    acc[j][1] += xf[j + 2] * wv2.y;
                    acc[j][2] += xf[j + 2] * wv2.z;
                    acc[j][3] += xf[j + 2] * wv2.w;
                }
            }
        }
        __syncthreads();
    }
#undef C3_STAGE

    float* pb = parts + (size_t)quarter * 4718592;
#pragma unroll
    for (int j = 0; j < 12; ++j) {
        float4 o = {acc[j][0], acc[j][1], acc[j][2], acc[j][3]};
        *(float4*)&pb[((size_t)n * L_ + (size_t)h * 96 + w0 + j) * 64 + cq0] = o;
    }
}

// ---------------- combine split-K partials + bias -> xe ----------------
__global__ __launch_bounds__(256) void k_c3sum(const float* __restrict__ parts,
                                               const float* __restrict__ bm,
                                               float* __restrict__ xe) {
    size_t i = (size_t)blockIdx.x * 256 + threadIdx.x;   // f4 index; grid 4608
    float4 a = ((const float4*)parts)[i];
    float4 b = ((const float4*)parts)[i + 1179648];
    float4 c = ((const float4*)parts)[i + 2359296];
    float4 d = ((const float4*)parts)[i + 3538944];
    float4 bi = ((const float4*)bm)[i & 15];
    float4 o = {((a.x + b.x) + c.x) + d.x + bi.x,
                ((a.y + b.y) + c.y) + d.y + bi.y,
                ((a.z + b.z) + c.z) + d.z + bi.z,
                ((a.w + b.w) + c.w) + d.w + bi.w};
    ((float4*)xe)[i] = o;
}

// ---------------- conv1x1 via bf16 MFMA -> yeb bf16 [8,9216,256] ----------------
__global__ __launch_bounds__(256) void k_conv1x1(const float* __restrict__ x,
                                                 const float* __restrict__ wa,
                                                 const float* __restrict__ ba,
                                                 unsigned short* __restrict__ yeb) {
    __shared__ __align__(16) unsigned short pA[64 * 40];  // [co][k], pad 40
    __shared__ __align__(16) unsigned short pB[32 * 68];  // [k][l],  pad 68
    __shared__ __align__(16) float det[64 * 67];          // [co][l], pad 67
    const int bid = blockIdx.x;
    const int n = bid / 576, rem = bid % 576;
    const int l0 = (rem >> 2) * 64, co0 = (rem & 3) * 64;
    const int t = threadIdx.x, lane = t & 63, nq = t >> 6;

    f32x4 acc[4];
#pragma unroll
    for (int nt = 0; nt < 4; ++nt) { f32x4 z = {0.f, 0.f, 0.f, 0.f}; acc[nt] = z; }

    const int aOff = (nq * 16 + (lane & 15)) * 40 + (lane >> 4) * 8;
    const int bK = (lane >> 4) * 8, bL = lane & 15;

    for (int kc = 0; kc < 8; ++kc) {
        const int c0 = kc * 32;
        __syncthreads();
        for (int s = t; s < 512; s += 256) {
            int co = s >> 3, q = s & 7;
            float4 v = *(const float4*)&wa[(size_t)(co0 + co) * 256 + c0 + q * 4];
            ushort4 b = {f2bf(v.x), f2bf(v.y), f2bf(v.z), f2bf(v.w)};
            *(ushort4*)&pA[co * 40 + q * 4] = b;
        }
        for (int s = t; s < 512; s += 256) {
            int c = s >> 4, l4 = s & 15;
            float4 v = *(const float4*)&x[((size_t)n * 256 + c0 + c) * L_ + l0 + l4 * 4];
            ushort4 b = {f2bf(v.x), f2bf(v.y), f2bf(v.z), f2bf(v.w)};
            *(ushort4*)&pB[c * 68 + l4 * 4] = b;
        }
        __syncthreads();
        u16x8 au = *(const u16x8*)&pA[aOff];
        bf16x8 af = __builtin_bit_cast(bf16x8, au);
#pragma unroll
        for (int nt = 0; nt < 4; ++nt) {
            u16x8 bu;
#pragma unroll
            for (int j = 0; j < 8; ++j) bu[j] = pB[(bK + j) * 68 + nt * 16 + bL];
            bf16x8 bf = __builtin_bit_cast(bf16x8, bu);
            acc[nt] = __builtin_amdgcn_mfma_f32_16x16x32_bf16(af, bf, acc[nt], 0, 0, 0);
        }
    }
    __syncthreads();
#pragma unroll
    for (int nt = 0; nt < 4; ++nt)
#pragma unroll
        for (int r = 0; r < 4; ++r)
            det[(nq * 16 + (lane >> 4) * 4 + r) * 67 + nt * 16 + (lane & 15)] = acc[nt][r];
    __syncthreads();
    for (int s = t; s < 512; s += 256) {
        int l = s >> 3, c8 = s & 7;       // 8 co per slot
        u16x8 o;
#pragma unroll
        for (int e = 0; e < 8; ++e) {
            int co = c8 * 8 + e;
            o[e] = f2bf(det[co * 67 + l] + ba[co0 + co]);
        }
        *(u16x8*)&yeb[((size_t)n * L_ + l0 + l) * 256 + co0 + c8 * 8] = o;
    }
}

// ---------------- kmeans assign (fp64 dot; norm is argmax-invariant) ----------------
__global__ __launch_bounds__(256) void k_assign(const float* __restrict__ xe,
                                                const float* __restrict__ means,
                                                int* __restrict__ codes_i,
                                                float* __restrict__ codes_f) {
    __shared__ float sm[128 * 64];
    for (int s = threadIdx.x; s < 8192; s += 256) sm[s] = means[s];
    __syncthreads();
    const int g = blockIdx.x * 256 + threadIdx.x;
    const float* row = xe + (size_t)g * 64;
    float v[64];
#pragma unroll
    for (int c4 = 0; c4 < 16; c4++) {
        float4 t4 = *(const float4*)(row + c4 * 4);
        v[c4 * 4 + 0] = t4.x; v[c4 * 4 + 1] = t4.y; v[c4 * 4 + 2] = t4.z; v[c4 * 4 + 3] = t4.w;
    }
    int best = 0;
    double bd = -1e300;
    for (int cl = 0; cl < 128; cl++) {
        double d = 0.0;
#pragma unroll
        for (int c4 = 0; c4 < 16; c4++) {
            float4 m4 = *(const float4*)(sm + cl * 64 + c4 * 4);
            d += (double)v[c4 * 4 + 0] * (double)m4.x + (double)v[c4 * 4 + 1] * (double)m4.y +
                 (double)v[c4 * 4 + 2] * (double)m4.z + (double)v[c4 * 4 + 3] * (double)m4.w;
        }
        if (d > bd) { bd = d; best = cl; }
    }
    codes_i[g] = best;
    codes_f[g] = (float)best;
}

// ---------------- stable counting sort ----------------
__global__ void k_hist(const int* __restrict__ codes_i, int* __restrict__ hist) {
    __shared__ int h[128];
    if (threadIdx.x < 128) h[threadIdx.x] = 0;
    __syncthreads();
    int n = blockIdx.x / 36, ch = blockIdx.x % 36;
    int c = codes_i[n * L_ + ch * 256 + threadIdx.x];
    atomicAdd(&h[c], 1);
    __syncthreads();
    if (threadIdx.x < 128) hist[(n * 36 + ch) * 128 + threadIdx.x] = h[threadIdx.x];
}

__global__ void k_scan(const int* __restrict__ hist, int* __restrict__ basebuf) {
    __shared__ int tot[128];
    __shared__ int binstart[128];
    int n = blockIdx.x, c = threadIdx.x;
    int run = 0;
    int local[36];
    for (int ch = 0; ch < 36; ch++) { local[ch] = run; run += hist[(n * 36 + ch) * 128 + c]; }
    tot[c] = run;
    __syncthreads();
    if (c == 0) {
        int s = 0;
        for (int b = 0; b < 128; b++) { binstart[b] = s; s += tot[b]; }
    }
    __syncthreads();
    int bs0 = binstart[c];
    for (int ch = 0; ch < 36; ch++) basebuf[(n * 36 + ch) * 128 + c] = bs0 + local[ch];
}

__global__ void k_rank(const int* __restrict__ codes_i, const int* __restrict__ basebuf,
                       int* __restrict__ idxb) {
    __shared__ int sc[256];
    __shared__ int sb[128];
    int n = blockIdx.x / 36, ch = blockIdx.x % 36;
    int i = threadIdx.x;
    int l = ch * 256 + i;
    int c = codes_i[n * L_ + l];
    sc[i] = c;
    if (i < 128) sb[i] = basebuf[(n * 36 + ch) * 128 + i];
    __syncthreads();
    int r = 0;
    for (int j = 0; j < i; j++) r += (sc[j] == c);
    int pos = sb[c] + r;
    idxb[n * L_ + pos] = l;
}

// ---------------- QK via bf16 MFMA + online softmax stats (r13 version) ----------
__global__ __launch_bounds__(256) void k_qk_mfma(const float* __restrict__ xe,
                                                 const int* __restrict__ idxb,
                                                 float* __restrict__ raw,
                                                 float* __restrict__ bs,
                                                 float* __restrict__ smaxb,
                                                 float* __restrict__ sinvb) {
    __shared__ __align__(16) unsigned short kb[432 * 72];
    __shared__ float snorm[144];
    __shared__ int sidx[432];
    __shared__ float pm[4][144], ps[4][144];
    const int bid = blockIdx.x;
    const int n = bid >> 6, k = bid & 63;
    const int t = threadIdx.x, lane = t & 63, nq = t >> 6;

    for (int s = t; s < 432; s += 256) {
        int wb = s / 144, jj = s % 144;
        int wk = (wb == 0) ? k : (wb == 1) ? ((k + 63) & 63) : ((k + 1) & 63);
        sidx[s] = idxb[n * L_ + wk * WIN + jj];
    }
    __syncthreads();
    for (int s = t; s < 6912; s += 256) {
        int row = s >> 4, q4 = s & 15;
        float4 v = *(const float4*)(xe + ((size_t)n * L_ + sidx[row]) * 64 + q4 * 4);
        float ss = v.x * v.x + v.y * v.y + v.z * v.z + v.w * v.w;
        ss += __shfl_xor(ss, 1); ss += __shfl_xor(ss, 2);
        ss += __shfl_xor(ss, 4); ss += __shfl_xor(ss, 8);
        float nr = fmaxf(sqrtf(ss), 5e-5f);
        float inv = 1.0f / nr;
        ushort4 b = {f2bf(v.x * inv), f2bf(v.y * inv), f2bf(v.z * inv), f2bf(v.w * inv)};
        *(ushort4*)&kb[row * 72 + q4 * 4] = b;
        if (q4 == 0 && row < 144) snorm[row] = nr;
    }
    __syncthreads();
    const int arow = lane & 15, aks = (lane >> 4) * 8;
    bf16x8 af[9][2];
#pragma unroll
    for (int mt = 0; mt < 9; ++mt) {
        af[mt][0] = *(const bf16x8*)&kb[(mt * 16 + arow) * 72 + aks];
        af[mt][1] = *(const bf16x8*)&kb[(mt * 16 + arow) * 72 + 32 + aks];
    }
    float sc[9][4];
#pragma unroll
    for (int mt = 0; mt < 9; ++mt)
#pragma unroll
        for (int r = 0; r < 4; ++r)
            sc[mt][r] = snorm[mt * 16 + (lane >> 4) * 4 + r];

    float rm[9][4], rs[9][4];
#pragma unroll
    for (int mt = 0; mt < 9; ++mt)
#pragma unroll
        for (int r = 0; r < 4; ++r) { rm[mt][r] = -1e30f; rs[mt][r] = 0.f; }

    float* rbase = raw + (size_t)(n * NWIN + k) * WIN * KJ;
    for (int nt = nq; nt < 27; nt += 4) {
        const int col = nt * 16 + (lane & 15);
        bf16x8 b0 = *(const bf16x8*)&kb[col * 72 + aks];
        bf16x8 b1 = *(const bf16x8*)&kb[col * 72 + 32 + aks];
#pragma unroll
        for (int mt = 0; mt < 9; ++mt) {
            f32x4 acc = {0.f, 0.f, 0.f, 0.f};
            acc = __builtin_amdgcn_mfma_f32_16x16x32_bf16(af[mt][0], b0, acc, 0, 0, 0);
            acc = __builtin_amdgcn_mfma_f32_16x16x32_bf16(af[mt][1], b1, acc, 0, 0, 0);
#pragma unroll
            for (int r = 0; r < 4; ++r) {
                float v = acc[r] * sc[mt][r];
                rbase[(size_t)(mt * 16 + (lane >> 4) * 4 + r) * KJ + col] = v;
                float mo = rm[mt][r];
                float mn = fmaxf(mo, v);
                rs[mt][r] = rs[mt][r] * __expf(mo - mn) + __expf(v - mn);
                rm[mt][r] = mn;
            }
        }
    }
#pragma unroll
    for (int mt = 0; mt < 9; ++mt)
#pragma unroll
        for (int r = 0; r < 4; ++r) {
            float m = rm[mt][r], s = rs[mt][r];
#pragma unroll
            for (int off = 1; off < 16; off <<= 1) {
                float om = __shfl_xor(m, off);
                float os = __shfl_xor(s, off);
                float M = fmaxf(m, om);
                s = s * __expf(m - M) + os * __expf(om - M);
                m = M;
            }
            rm[mt][r] = m; rs[mt][r] = s;
        }
    if ((lane & 15) == 0) {
#pragma unroll
        for (int mt = 0; mt < 9; ++mt)
#pragma unroll
            for (int r = 0; r < 4; ++r) {
                int row = mt * 16 + (lane >> 4) * 4 + r;
                pm[nq][row] = rm[mt][r];
                ps[nq][row] = rs[mt][r];
            }
    }
    __syncthreads();
    if (t < 144) {
        float M = pm[0][t], S = ps[0][t];
#pragma unroll
        for (int w = 1; w < 4; ++w) {
            float m2 = pm[w][t], s2 = ps[w][t];
            float Mn = fmaxf(M, m2);
            S = S * __expf(M - Mn) + s2 * __expf(m2 - Mn);
            M = Mn;
        }
        size_t o = (size_t)(n * NWIN + k) * WIN + t;
        bs[o] = M + logf(S);
        smaxb[o] = M;
        sinvb[o] = 1.f / S;
    }
}

// ---------------- PV + softmax-apply (r13 version) ----------------
__global__ __launch_bounds__(256) void k_pv_sm(const unsigned short* __restrict__ yeb,
                                               const int* __restrict__ idxb,
                                               float* __restrict__ score,
                                               const float* __restrict__ smaxb,
                                               const float* __restrict__ sinvb,
                                               unsigned short* __restrict__ retb) {
    __shared__ __align__(16) unsigned short pA[144 * 72];   // P[i][kk], stride 72
    __shared__ __align__(16) unsigned short pB[64 * 264];   // Y[kk][co], stride 264
    __shared__ int sidx[432];
    __shared__ float smax[144], sinv[144];
    const int bid = blockIdx.x;
    const int n = bid >> 6, k = bid & 63;
    const int t = threadIdx.x, lane = t & 63, nq = t >> 6;

    for (int s = t; s < 432; s += 256) {
        int wb = s / 144, jj = s % 144;
        int wk = (wb == 0) ? k : (wb == 1) ? ((k + 63) & 63) : ((k + 1) & 63);
        sidx[s] = idxb[n * L_ + wk * WIN + jj];
    }
    if (t < 144) {
        size_t o = (size_t)(n * NWIN + k) * WIN + t;
        smax[t] = smaxb[o];
        sinv[t] = sinvb[o];
    }

    f32x4 acc[9][4];
#pragma unroll
    for (int mt = 0; mt < 9; ++mt)
#pragma unroll
        for (int nt = 0; nt < 4; ++nt) {
            f32x4 z = {0.f, 0.f, 0.f, 0.f};
            acc[mt][nt] = z;
        }

    float* srow = score + (size_t)(n * NWIN + k) * WIN * KJ;
    const int aBase = (lane & 15) * 72 + (lane >> 4) * 8;
    const int bBase = (lane >> 4) * 8 * 264 + nq * 64 + (lane & 15);

    for (int kc = 0; kc < 7; ++kc) {
        __syncthreads();
        for (int s = t; s < 2304; s += 256) {
            int i = s >> 4, c4 = s & 15;
            int kcol = kc * 64 + c4 * 4;
            ushort4 b = {0, 0, 0, 0};
            if (kcol < KJ) {
                float4 v = *(const float4*)(srow + (size_t)i * KJ + kcol);
                float m = smax[i], iv = sinv[i];
                float4 p = {__expf(v.x - m) * iv, __expf(v.y - m) * iv,
                            __expf(v.z - m) * iv, __expf(v.w - m) * iv};
                *(float4*)(srow + (size_t)i * KJ + kcol) = p;
                b.x = f2bf(p.x); b.y = f2bf(p.y); b.z = f2bf(p.z); b.w = f2bf(p.w);
            }
            *(ushort4*)&pA[i * 72 + c4 * 4] = b;
        }
        for (int s = t; s < 2048; s += 256) {
            int j = s >> 5, c8 = s & 31;
            int kk = kc * 64 + j;
            u16x8 u = {0, 0, 0, 0, 0, 0, 0, 0};
            if (kk < KJ) u = *(const u16x8*)&yeb[(size_t)sidx[kk] * 256 +
                                                (size_t)n * L_ * 256 + c8 * 8];
            *(u16x8*)&pB[j * 264 + c8 * 8] = u;
        }
        __syncthreads();
#pragma unroll
        for (int ks = 0; ks < 2; ++ks) {
            bf16x8 af[9];
#pragma unroll
            for (int mt = 0; mt < 9; ++mt)
                af[mt] = *(const bf16x8*)&pA[aBase + mt * 1152 + ks * 32];
#pragma unroll
            for (int nt = 0; nt < 4; ++nt) {
                const int e = bBase + ks * 32 * 264 + nt * 16;
                u16x8 bu;
#pragma unroll
                for (int j = 0; j < 8; ++j) bu[j] = pB[e + j * 264];
                bf16x8 bf = __builtin_bit_cast(bf16x8, bu);
#pragma unroll
                for (int mt = 0; mt < 9; ++mt)
                    acc[mt][nt] = __builtin_amdgcn_mfma_f32_16x16x32_bf16(af[mt], bf, acc[mt][nt], 0, 0, 0);
            }
        }
    }
    const int rowb = (lane >> 4) * 4;
    const int colb = nq * 64 + (lane & 15);
#pragma unroll
    for (int mt = 0; mt < 9; ++mt)
#pragma unroll
        for (int nt = 0; nt < 4; ++nt)
#pragma unroll
            for (int r = 0; r < 4; ++r) {
                int row = mt * 16 + rowb + r;
                int tok = sidx[row];
                retb[((size_t)n * L_ + tok) * 256 + colb + nt * 16] = f2bf(acc[mt][nt][r]);
            }
}

// ---------------- final: out = x + 0.1 * retb (token order, bf16) ----------------
__global__ __launch_bounds__(256) void k_out(const float* __restrict__ x,
                                             const unsigned short* __restrict__ retb,
                                             float* __restrict__ out) {
    __shared__ float sr[32 * 257];
    const int n = blockIdx.x / 288, lt = blockIdx.x % 288;
    const int lbase = lt * 32;
    const int t = threadIdx.x;
    for (int s = t; s < 1024; s += 256) {
        int lr = s >> 5, c8 = s & 31;
        u16x8 u = *(const u16x8*)&retb[((size_t)n * L_ + lbase + lr) * 256 + c8 * 8];
#pragma unroll
        for (int e = 0; e < 8; ++e) sr[lr * 257 + c8 * 8 + e] = bf2f(u[e]);
    }
    __syncthreads();
    const int lr = t & 31, cog = t >> 5;
    for (int cc = 0; cc < 32; cc++) {
        int co = cog * 32 + cc;
        size_t gi = ((size_t)(n * 256 + co)) * L_ + lbase + lr;
        out[gi] = x[gi] + 0.1f * sr[lr * 257 + co];
    }
}

extern "C" void kernel_launch(void* const* d_in, const int* in_sizes, int n_in,
                              void* d_out, int out_size, void* d_ws, size_t ws_size,
                              hipStream_t stream) {
    (void)in_sizes; (void)n_in; (void)out_size; (void)ws_size;
    const float* x     = (const float*)d_in[0];
    const float* means = (const float*)d_in[1];
    const float* wm    = (const float*)d_in[2];
    const float* bm    = (const float*)d_in[3];
    const float* wa    = (const float*)d_in[4];
    const float* ba    = (const float*)d_in[5];

    float* out   = (float*)d_out;
    float* score = out + (size_t)8 * 256 * L_;
    float* bs    = score + (size_t)8 * NWIN * WIN * KJ;
    float* codesf = bs + (size_t)8 * L_;

    float* xe  = (float*)d_ws;
    float* ye  = xe + (size_t)8 * L_ * 64;                  // region reused as bf16 yeb
    float* ret = ye + (size_t)8 * L_ * 256;                 // parts (f32 x4) then retb (bf16)
    float* wtr = ret + (size_t)8 * L_ * 256;
    int* codes_i = (int*)(wtr + 147456);
    int* idxb    = codes_i + 8 * L_;
    int* undo    = idxb + 8 * L_;                           // unused, keeps layout
    int* hist    = undo + 8 * L_;
    int* basebuf = hist + 8 * 36 * 128;
    float* zeros = (float*)(basebuf + 8 * 36 * 128);
    float* smaxb = zeros + 64;                              // 512*144 f32
    float* sinvb = smaxb + 73728;                           // 512*144 f32

    float* parts = ret;
    unsigned short* yeb  = (unsigned short*)ye;
    unsigned short* retb = (unsigned short*)ret;

    k_wprep  <<<576, 256, 0, stream>>>(wm, wtr, zeros);
    k_conv3x3<<<1536, 256, 0, stream>>>(x, wtr, zeros, parts);
    k_c3sum  <<<4608, 256, 0, stream>>>(parts, bm, xe);
    k_conv1x1<<<4608, 256, 0, stream>>>(x, wa, ba, yeb);
    k_assign <<<288, 256, 0, stream>>>(xe, means, codes_i, codesf);
    k_hist   <<<288, 256, 0, stream>>>(codes_i, hist);
    k_scan   <<<8, 128, 0, stream>>>(hist, basebuf);
    k_rank   <<<288, 256, 0, stream>>>(codes_i, basebuf, idxb);
    k_qk_mfma<<<512, 256, 0, stream>>>(xe, idxb, score, bs, smaxb, sinvb);
    k_pv_sm  <<<512, 256, 0, stream>>>(yeb, idxb, score, smaxb, sinvb, retb);
    k_out    <<<2304, 256, 0, stream>>>(x, retb, out);
}